// Round 2
// baseline (4989.994 us; speedup 1.0000x reference)
//
#include <hip/hip_runtime.h>

#define TSTEPS 512
#define BATCH  64
#define DIN    256
#define DLAT   512

// ---------------- Kernel A: P[m,n] = x[m,:] . W_in[n,:] + b_h[n] ----------------
// M = TSTEPS*BATCH = 32768, K = DIN = 256, N = DLAT = 512. Writes into d_out.
#define BM 64
#define BN 64
#define BK 32

__global__ __launch_bounds__(256)
void precompute_gemm(const float* __restrict__ x,
                     const float* __restrict__ Win,
                     const float* __restrict__ bh,
                     float* __restrict__ P)
{
    __shared__ float As[BM][BK + 1];   // +1 pad: breaks 16-way bank conflict
    __shared__ float Ws[BN][BK + 1];
    const int m0  = blockIdx.y * BM;
    const int n0  = blockIdx.x * BN;
    const int tid = threadIdx.x;
    const int tx  = tid & 15;          // n-direction (x4)
    const int ty  = tid >> 4;          // m-direction (x4)
    const int lr  = tid >> 2;          // loader row 0..63
    const int lc  = (tid & 3) * 8;     // loader col 0,8,16,24

    float acc[4][4] = {};

    for (int kk = 0; kk < DIN; kk += BK) {
        const float* ax = x   + (size_t)(m0 + lr) * DIN + kk + lc;
        const float* aw = Win + (size_t)(n0 + lr) * DIN + kk + lc;
        float4 a0 = *(const float4*)(ax);
        float4 a1 = *(const float4*)(ax + 4);
        float4 w0 = *(const float4*)(aw);
        float4 w1 = *(const float4*)(aw + 4);
        As[lr][lc+0]=a0.x; As[lr][lc+1]=a0.y; As[lr][lc+2]=a0.z; As[lr][lc+3]=a0.w;
        As[lr][lc+4]=a1.x; As[lr][lc+5]=a1.y; As[lr][lc+6]=a1.z; As[lr][lc+7]=a1.w;
        Ws[lr][lc+0]=w0.x; Ws[lr][lc+1]=w0.y; Ws[lr][lc+2]=w0.z; Ws[lr][lc+3]=w0.w;
        Ws[lr][lc+4]=w1.x; Ws[lr][lc+5]=w1.y; Ws[lr][lc+6]=w1.z; Ws[lr][lc+7]=w1.w;
        __syncthreads();
        #pragma unroll
        for (int k = 0; k < BK; ++k) {
            float a[4], w[4];
            #pragma unroll
            for (int i = 0; i < 4; ++i) a[i] = As[ty*4+i][k];
            #pragma unroll
            for (int j = 0; j < 4; ++j) w[j] = Ws[tx*4+j][k];
            #pragma unroll
            for (int i = 0; i < 4; ++i)
                #pragma unroll
                for (int j = 0; j < 4; ++j)
                    acc[i][j] += a[i] * w[j];
        }
        __syncthreads();
    }

    float4 bv = *(const float4*)(bh + n0 + tx*4);
    #pragma unroll
    for (int i = 0; i < 4; ++i) {
        float4 v;
        v.x = acc[i][0] + bv.x; v.y = acc[i][1] + bv.y;
        v.z = acc[i][2] + bv.z; v.w = acc[i][3] + bv.w;
        *(float4*)(P + (size_t)(m0 + ty*4 + i) * DLAT + n0 + tx*4) = v;
    }
}

// ---------------- Transpose W_h (512x512) into d_ws: Wt[k][r] = W_h[r][k] --------
__global__ __launch_bounds__(256)
void transpose512(const float* __restrict__ in, float* __restrict__ out)
{
    __shared__ float tile[32][33];
    const int x0 = blockIdx.x * 32, y0 = blockIdx.y * 32;
    const int tx = threadIdx.x, ty = threadIdx.y;   // (32, 8)
    #pragma unroll
    for (int j = 0; j < 32; j += 8)
        tile[ty + j][tx] = in[(size_t)(y0 + ty + j) * DLAT + x0 + tx];
    __syncthreads();
    #pragma unroll
    for (int j = 0; j < 32; j += 8)
        out[(size_t)(x0 + ty + j) * DLAT + y0 + tx] = tile[tx][ty + j];
}

// ---------------- Kernel B: sequential scan with exact relu-sparsity skipping ----
// One batch row per WG (64 WGs, sync-free chains). Per step, only the k rows of
// Wt with h[k] != 0 are streamed from L2 (exact — zero contributions skipped).
// After relu ~50% of h is 0 -> ~2x less L2 traffic (the measured bottleneck:
// per-CU L2 port ~64 B/cyc).
// Layout: 1024 threads = 4 list-quarter groups x 256 threads; thread owns output
// rows (2*lr, 2*lr+1), float2 weight loads. Compaction is ballot-based and
// deterministic (no atomics -> fixed summation order across replays).
__global__ __launch_bounds__(1024)
void rnn_scan_sparse(const float* __restrict__ Wt,   // [DLAT k][DLAT r]
                     const float* __restrict__ h0,
                     float* __restrict__ out)
{
    __shared__ float h[DLAT];
    __shared__ float p[4][DLAT];
    __shared__ int   idxl[DLAT];
    __shared__ int   wcnt[8];

    const int b    = blockIdx.x;
    const int tid  = threadIdx.x;
    const int g    = tid >> 8;          // 0..3  (list quarter)
    const int lr   = tid & 255;         // 0..255 (row pair)
    const int r2   = lr * 2;
    const int wv   = tid >> 6;          // wave 0..15
    const int lane = tid & 63;

    // ---- init: h = h0 (pre-relu; negatives DO contribute), compact k != 0 ----
    float v0 = 0.f;
    if (tid < DLAT) { v0 = h0[(size_t)b * DLAT + tid]; h[tid] = v0; }
    bool flag = (tid < DLAT) && (v0 != 0.f);
    unsigned long long mask = __ballot(flag);
    if (lane == 0 && wv < 8) wcnt[wv] = __popcll(mask);
    __syncthreads();
    int nnz = 0;
    #pragma unroll
    for (int w = 0; w < 8; ++w) nnz += wcnt[w];
    if (flag) {
        int base = __popcll(mask & ((1ull << lane) - 1ull));
        for (int w = 0; w < wv; ++w) base += wcnt[w];
        idxl[base] = tid;
    }
    __syncthreads();

    const float* wb = Wt + r2;

    for (int t = 0; t < TSTEPS; ++t) {
        // ---- sparse accumulate over this group's quarter of the nnz list ----
        const int sg = (nnz * g) >> 2;
        const int eg = (nnz * (g + 1)) >> 2;
        float ax = 0.f, ay = 0.f;
        int i = sg;
        for (; i + 4 <= eg; i += 4) {
            int k0 = idxl[i], k1 = idxl[i+1], k2 = idxl[i+2], k3 = idxl[i+3];
            float hv0 = h[k0], hv1 = h[k1], hv2 = h[k2], hv3 = h[k3];
            float2 w0 = *(const float2*)(wb + (size_t)k0 * DLAT);
            float2 w1 = *(const float2*)(wb + (size_t)k1 * DLAT);
            float2 w2 = *(const float2*)(wb + (size_t)k2 * DLAT);
            float2 w3 = *(const float2*)(wb + (size_t)k3 * DLAT);
            ax += hv0 * w0.x; ay += hv0 * w0.y;
            ax += hv1 * w1.x; ay += hv1 * w1.y;
            ax += hv2 * w2.x; ay += hv2 * w2.y;
            ax += hv3 * w3.x; ay += hv3 * w3.y;
        }
        for (; i < eg; ++i) {
            int k = idxl[i]; float hv = h[k];
            float2 w = *(const float2*)(wb + (size_t)k * DLAT);
            ax += hv * w.x; ay += hv * w.y;
        }
        *(float2*)&p[g][r2] = make_float2(ax, ay);
        __syncthreads();   // accum done: p ready; h/idxl reads complete

        // ---- epilogue: v = relu(P + sum p) ; write out & h; ballot-compact ----
        float v = 0.f;
        if (tid < DLAT) {
            float* orow = out + ((size_t)t * BATCH + b) * DLAT;
            v = orow[tid] + p[0][tid] + p[1][tid] + p[2][tid] + p[3][tid];
            v = fmaxf(v, 0.f);
            h[tid]    = v;
            orow[tid] = v;
        }
        bool f2 = (tid < DLAT) && (v > 0.f);
        unsigned long long m2 = __ballot(f2);
        if (lane == 0 && wv < 8) wcnt[wv] = __popcll(m2);
        __syncthreads();   // wcnt ready
        nnz = 0;
        #pragma unroll
        for (int w = 0; w < 8; ++w) nnz += wcnt[w];
        if (f2) {
            int base = __popcll(m2 & ((1ull << lane) - 1ull));
            for (int w = 0; w < wv; ++w) base += wcnt[w];
            idxl[base] = tid;
        }
        __syncthreads();   // idxl ready for next step
    }
}

// ---------------- Fallback (no workspace): row-major W_h, one row per thread ----
__global__ __launch_bounds__(512)
void rnn_scan_row(const float* __restrict__ Wh,
                  const float* __restrict__ h0,
                  float* __restrict__ out)
{
    __shared__ float h[DLAT];
    const int b = blockIdx.x;
    const int r = threadIdx.x;
    h[r] = h0[(size_t)b * DLAT + r];
    __syncthreads();
    const float* wrow = Wh + (size_t)r * DLAT;
    for (int t = 0; t < TSTEPS; ++t) {
        float* orow = out + ((size_t)t * BATCH + b) * DLAT;
        float acc = orow[r];
        #pragma unroll 8
        for (int k = 0; k < DLAT; k += 4) {
            float4 w  = *(const float4*)(wrow + k);
            float4 hv = *(const float4*)&h[k];
            acc += w.x*hv.x + w.y*hv.y + w.z*hv.z + w.w*hv.w;
        }
        float v = fmaxf(acc, 0.f);
        __syncthreads();
        h[r] = v;
        orow[r] = v;
        __syncthreads();
    }
}

extern "C" void kernel_launch(void* const* d_in, const int* in_sizes, int n_in,
                              void* d_out, int out_size, void* d_ws, size_t ws_size,
                              hipStream_t stream)
{
    const float* x    = (const float*)d_in[0];
    const float* h0   = (const float*)d_in[1];
    const float* Win  = (const float*)d_in[2];
    const float* Wh   = (const float*)d_in[3];
    const float* bh   = (const float*)d_in[4];
    float* out = (float*)d_out;

    dim3 gA(DLAT / BN, (TSTEPS * BATCH) / BM);   // (8, 512)
    precompute_gemm<<<gA, 256, 0, stream>>>(x, Win, bh, out);

    if (ws_size >= (size_t)DLAT * DLAT * sizeof(float)) {
        float* Wt = (float*)d_ws;
        transpose512<<<dim3(16, 16), dim3(32, 8), 0, stream>>>(Wh, Wt);
        rnn_scan_sparse<<<BATCH, 1024, 0, stream>>>(Wt, h0, out);
    } else {
        rnn_scan_row<<<BATCH, 512, 0, stream>>>(Wh, h0, out);
    }
}

// Round 3
// 2230.161 us; speedup vs baseline: 2.2375x; 2.2375x over previous
//
#include <hip/hip_runtime.h>

#define TSTEPS 512
#define BATCH  64
#define DIN    256
#define DLAT   512

typedef _Float16 half2_t __attribute__((ext_vector_type(2)));
typedef _Float16 half8_t __attribute__((ext_vector_type(8)));

#if __has_builtin(__builtin_amdgcn_fdot2)
#define FDOT2(a, b, c) __builtin_amdgcn_fdot2((a), (b), (c), false)
#else
#define FDOT2(a, b, c) fmaf((float)(a)[0], (float)(b)[0], fmaf((float)(a)[1], (float)(b)[1], (c)))
#endif

// ---------------- Kernel A: P[m,n] = x[m,:] . W_in[n,:] + b_h[n] ----------------
// M = TSTEPS*BATCH = 32768, K = DIN = 256, N = DLAT = 512. Writes into d_out.
#define BM 64
#define BN 64
#define BK 32

__global__ __launch_bounds__(256)
void precompute_gemm(const float* __restrict__ x,
                     const float* __restrict__ Win,
                     const float* __restrict__ bh,
                     float* __restrict__ P)
{
    __shared__ float As[BM][BK + 1];   // +1 pad: breaks 16-way bank conflict
    __shared__ float Ws[BN][BK + 1];
    const int m0  = blockIdx.y * BM;
    const int n0  = blockIdx.x * BN;
    const int tid = threadIdx.x;
    const int tx  = tid & 15;          // n-direction (x4)
    const int ty  = tid >> 4;          // m-direction (x4)
    const int lr  = tid >> 2;          // loader row 0..63
    const int lc  = (tid & 3) * 8;     // loader col 0,8,16,24

    float acc[4][4] = {};

    for (int kk = 0; kk < DIN; kk += BK) {
        const float* ax = x   + (size_t)(m0 + lr) * DIN + kk + lc;
        const float* aw = Win + (size_t)(n0 + lr) * DIN + kk + lc;
        float4 a0 = *(const float4*)(ax);
        float4 a1 = *(const float4*)(ax + 4);
        float4 w0 = *(const float4*)(aw);
        float4 w1 = *(const float4*)(aw + 4);
        As[lr][lc+0]=a0.x; As[lr][lc+1]=a0.y; As[lr][lc+2]=a0.z; As[lr][lc+3]=a0.w;
        As[lr][lc+4]=a1.x; As[lr][lc+5]=a1.y; As[lr][lc+6]=a1.z; As[lr][lc+7]=a1.w;
        Ws[lr][lc+0]=w0.x; Ws[lr][lc+1]=w0.y; Ws[lr][lc+2]=w0.z; Ws[lr][lc+3]=w0.w;
        Ws[lr][lc+4]=w1.x; Ws[lr][lc+5]=w1.y; Ws[lr][lc+6]=w1.z; Ws[lr][lc+7]=w1.w;
        __syncthreads();
        #pragma unroll
        for (int k = 0; k < BK; ++k) {
            float a[4], w[4];
            #pragma unroll
            for (int i = 0; i < 4; ++i) a[i] = As[ty*4+i][k];
            #pragma unroll
            for (int j = 0; j < 4; ++j) w[j] = Ws[tx*4+j][k];
            #pragma unroll
            for (int i = 0; i < 4; ++i)
                #pragma unroll
                for (int j = 0; j < 4; ++j)
                    acc[i][j] += a[i] * w[j];
        }
        __syncthreads();
    }

    float4 bv = *(const float4*)(bh + n0 + tx*4);
    #pragma unroll
    for (int i = 0; i < 4; ++i) {
        float4 v;
        v.x = acc[i][0] + bv.x; v.y = acc[i][1] + bv.y;
        v.z = acc[i][2] + bv.z; v.w = acc[i][3] + bv.w;
        *(float4*)(P + (size_t)(m0 + ty*4 + i) * DLAT + n0 + tx*4) = v;
    }
}

// -------- Pack W_h (512x512 fp32 row-major [r][k]) into fp16 k-pair layout -------
// Wp2[kp][r] = half2( W_h[r][2kp], W_h[r][2kp+1] ), kp in [0,256), r in [0,512).
// Row of Wp2 (fixed kp) is 512 half2 = 2KB contiguous -> scan loads are fully
// coalesced dwordx4 (1KB per wave-instr), same streaming shape as the fp32 kernel.
__global__ __launch_bounds__(256)
void pack_wh_fp16(const float* __restrict__ Wh, half2_t* __restrict__ Wp2)
{
    __shared__ float tile[32][33];
    const int x0 = blockIdx.x * 32;    // k tile
    const int y0 = blockIdx.y * 32;    // r tile
    const int tx = threadIdx.x, ty = threadIdx.y;   // (32, 8)
    #pragma unroll
    for (int j = 0; j < 32; j += 8)
        tile[ty + j][tx] = Wh[(size_t)(y0 + ty + j) * DLAT + x0 + tx]; // tile[r][k]
    __syncthreads();
    #pragma unroll
    for (int j = 0; j < 16; j += 8) {
        const int kp = ty + j;                       // 0..15
        half2_t v;
        v[0] = (_Float16)tile[tx][2 * kp];
        v[1] = (_Float16)tile[tx][2 * kp + 1];
        Wp2[(size_t)((x0 >> 1) + kp) * DLAT + y0 + tx] = v;
    }
}

// ---------------- Kernel B: sequential scan, fp16 weights, dot2 accumulate -------
// One batch row per WG (64 sync-free chains). Dense streaming: per step each WG
// reads 512KB (half the fp32 version) with the identical coalesced deep-unrolled
// pattern. 1024 threads = 8 k-pair groups x 128 threads; thread owns 4 output
// rows, loads one dwordx4 (4 half2) per k-pair, v_dot2_f32_f16 into fp32 acc.
// Epilogue (P + partials + relu) stays fully fp32; only multiply inputs are fp16.
__global__ __launch_bounds__(1024)
void rnn_scan_fp16(const half2_t* __restrict__ Wp2,  // [256 kp][512 r]
                   const float* __restrict__ h0,
                   float* __restrict__ out)
{
    __shared__ float    p[8][DLAT];        // 16 KB partials
    __shared__ half2_t  hh[DLAT / 2];      // 1 KB: hh[k2] = (h[2k2], h[2k2+1])
    const int b   = blockIdx.x;
    const int tid = threadIdx.x;
    const int kq  = tid >> 7;              // 0..7: k-pairs [kq*32, kq*32+32)
    const int g   = tid & 127;             // 0..127
    const int r4  = g * 4;                 // output rows r4..r4+3

    if (tid < DLAT) {
        float v = h0[(size_t)b * DLAT + tid];
        ((_Float16*)hh)[tid] = (_Float16)v;
    }
    __syncthreads();

    // wbase in half8 units: one half8 = 4 half2 = 16B; row stride (per kp) = 128 half8
    const half8_t* wbase = (const half8_t*)(Wp2 + (size_t)(kq * 32) * DLAT + r4);

    for (int t = 0; t < TSTEPS; ++t) {
        float4 acc = make_float4(0.f, 0.f, 0.f, 0.f);
        #pragma unroll 8
        for (int i = 0; i < 32; ++i) {
            half2_t hv = hh[kq * 32 + i];          // broadcast (free)
            half8_t w  = wbase[(size_t)i * 128];   // 16B coalesced, 1KB/wave-instr
            half2_t w0 = {w[0], w[1]};
            half2_t w1 = {w[2], w[3]};
            half2_t w2 = {w[4], w[5]};
            half2_t w3 = {w[6], w[7]};
            acc.x = FDOT2(w0, hv, acc.x);
            acc.y = FDOT2(w1, hv, acc.y);
            acc.z = FDOT2(w2, hv, acc.z);
            acc.w = FDOT2(w3, hv, acc.w);
        }
        *(float4*)&p[kq][r4] = acc;
        __syncthreads();   // partials ready; hh reads of this step complete

        if (tid < DLAT) {
            float* orow = out + ((size_t)t * BATCH + b) * DLAT;
            float v = orow[tid];
            #pragma unroll
            for (int q = 0; q < 8; ++q) v += p[q][tid];
            v = fmaxf(v, 0.f);
            orow[tid] = v;
            ((_Float16*)hh)[tid] = (_Float16)v;    // fp16 copy for next step
        }
        __syncthreads();   // hh ready
    }
}

// ---------------- Fallback (no workspace): row-major W_h, one row per thread ----
__global__ __launch_bounds__(512)
void rnn_scan_row(const float* __restrict__ Wh,
                  const float* __restrict__ h0,
                  float* __restrict__ out)
{
    __shared__ float h[DLAT];
    const int b = blockIdx.x;
    const int r = threadIdx.x;
    h[r] = h0[(size_t)b * DLAT + r];
    __syncthreads();
    const float* wrow = Wh + (size_t)r * DLAT;
    for (int t = 0; t < TSTEPS; ++t) {
        float* orow = out + ((size_t)t * BATCH + b) * DLAT;
        float acc = orow[r];
        #pragma unroll 8
        for (int k = 0; k < DLAT; k += 4) {
            float4 w  = *(const float4*)(wrow + k);
            float4 hv = *(const float4*)&h[k];
            acc += w.x*hv.x + w.y*hv.y + w.z*hv.z + w.w*hv.w;
        }
        float v = fmaxf(acc, 0.f);
        __syncthreads();
        h[r] = v;
        orow[r] = v;
        __syncthreads();
    }
}

extern "C" void kernel_launch(void* const* d_in, const int* in_sizes, int n_in,
                              void* d_out, int out_size, void* d_ws, size_t ws_size,
                              hipStream_t stream)
{
    const float* x    = (const float*)d_in[0];
    const float* h0   = (const float*)d_in[1];
    const float* Win  = (const float*)d_in[2];
    const float* Wh   = (const float*)d_in[3];
    const float* bh   = (const float*)d_in[4];
    float* out = (float*)d_out;

    dim3 gA(DLAT / BN, (TSTEPS * BATCH) / BM);   // (8, 512)
    precompute_gemm<<<gA, 256, 0, stream>>>(x, Win, bh, out);

    const size_t wp_bytes = (size_t)(DLAT / 2) * DLAT * sizeof(half2_t);  // 512 KB
    if (ws_size >= wp_bytes) {
        half2_t* Wp2 = (half2_t*)d_ws;
        pack_wh_fp16<<<dim3(16, 16), dim3(32, 8), 0, stream>>>(Wh, Wp2);
        rnn_scan_fp16<<<BATCH, 1024, 0, stream>>>(Wp2, h0, out);
    } else {
        rnn_scan_row<<<BATCH, 512, 0, stream>>>(Wh, h0, out);
    }
}

// Round 4
// 872.128 us; speedup vs baseline: 5.7216x; 2.5571x over previous
//
#include <hip/hip_runtime.h>

#define TSTEPS 512
#define BATCH  64
#define DIN    256
#define DLAT   512

typedef _Float16 half2_t __attribute__((ext_vector_type(2)));
typedef _Float16 half8_t __attribute__((ext_vector_type(8)));

#if __has_builtin(__builtin_amdgcn_fdot2)
#define FDOT2(a, b, c) __builtin_amdgcn_fdot2((a), (b), (c), false)
#else
#define FDOT2(a, b, c) fmaf((float)(a)[0], (float)(b)[0], fmaf((float)(a)[1], (float)(b)[1], (c)))
#endif

// dot2 of one half8 weight word (4 rows x 1 k-pair) against h k-pair hv
#define DOT4(wv, hv)                                              \
    do {                                                          \
        half2_t _w0 = {(wv)[0], (wv)[1]};                         \
        half2_t _w1 = {(wv)[2], (wv)[3]};                         \
        half2_t _w2 = {(wv)[4], (wv)[5]};                         \
        half2_t _w3 = {(wv)[6], (wv)[7]};                         \
        acc.x = FDOT2(_w0, (hv), acc.x);                          \
        acc.y = FDOT2(_w1, (hv), acc.y);                          \
        acc.z = FDOT2(_w2, (hv), acc.z);                          \
        acc.w = FDOT2(_w3, (hv), acc.w);                          \
    } while (0)

// ---------------- Kernel A: P[m,n] = x[m,:] . W_in[n,:] + b_h[n] ----------------
#define BM 64
#define BN 64
#define BK 32

__global__ __launch_bounds__(256)
void precompute_gemm(const float* __restrict__ x,
                     const float* __restrict__ Win,
                     const float* __restrict__ bh,
                     float* __restrict__ P)
{
    __shared__ float As[BM][BK + 1];
    __shared__ float Ws[BN][BK + 1];
    const int m0  = blockIdx.y * BM;
    const int n0  = blockIdx.x * BN;
    const int tid = threadIdx.x;
    const int tx  = tid & 15;
    const int ty  = tid >> 4;
    const int lr  = tid >> 2;
    const int lc  = (tid & 3) * 8;

    float acc[4][4] = {};

    for (int kk = 0; kk < DIN; kk += BK) {
        const float* ax = x   + (size_t)(m0 + lr) * DIN + kk + lc;
        const float* aw = Win + (size_t)(n0 + lr) * DIN + kk + lc;
        float4 a0 = *(const float4*)(ax);
        float4 a1 = *(const float4*)(ax + 4);
        float4 w0 = *(const float4*)(aw);
        float4 w1 = *(const float4*)(aw + 4);
        As[lr][lc+0]=a0.x; As[lr][lc+1]=a0.y; As[lr][lc+2]=a0.z; As[lr][lc+3]=a0.w;
        As[lr][lc+4]=a1.x; As[lr][lc+5]=a1.y; As[lr][lc+6]=a1.z; As[lr][lc+7]=a1.w;
        Ws[lr][lc+0]=w0.x; Ws[lr][lc+1]=w0.y; Ws[lr][lc+2]=w0.z; Ws[lr][lc+3]=w0.w;
        Ws[lr][lc+4]=w1.x; Ws[lr][lc+5]=w1.y; Ws[lr][lc+6]=w1.z; Ws[lr][lc+7]=w1.w;
        __syncthreads();
        #pragma unroll
        for (int k = 0; k < BK; ++k) {
            float a[4], w[4];
            #pragma unroll
            for (int i = 0; i < 4; ++i) a[i] = As[ty*4+i][k];
            #pragma unroll
            for (int j = 0; j < 4; ++j) w[j] = Ws[tx*4+j][k];
            #pragma unroll
            for (int i = 0; i < 4; ++i)
                #pragma unroll
                for (int j = 0; j < 4; ++j)
                    acc[i][j] += a[i] * w[j];
        }
        __syncthreads();
    }

    float4 bv = *(const float4*)(bh + n0 + tx*4);
    #pragma unroll
    for (int i = 0; i < 4; ++i) {
        float4 v;
        v.x = acc[i][0] + bv.x; v.y = acc[i][1] + bv.y;
        v.z = acc[i][2] + bv.z; v.w = acc[i][3] + bv.w;
        *(float4*)(P + (size_t)(m0 + ty*4 + i) * DLAT + n0 + tx*4) = v;
    }
}

// -------- Pack W_h (512x512 fp32 row-major [r][k]) into fp16 k-pair layout -------
// Wp2[kp][r] = half2( W_h[r][2kp], W_h[r][2kp+1] ), kp in [0,256), r in [0,512).
__global__ __launch_bounds__(256)
void pack_wh_fp16(const float* __restrict__ Wh, half2_t* __restrict__ Wp2)
{
    __shared__ float tile[32][33];
    const int x0 = blockIdx.x * 32;    // k tile
    const int y0 = blockIdx.y * 32;    // r tile
    const int tx = threadIdx.x, ty = threadIdx.y;   // (32, 8)
    #pragma unroll
    for (int j = 0; j < 32; j += 8)
        tile[ty + j][tx] = Wh[(size_t)(y0 + ty + j) * DLAT + x0 + tx]; // tile[r][k]
    __syncthreads();
    #pragma unroll
    for (int j = 0; j < 16; j += 8) {
        const int kp = ty + j;                       // 0..15
        half2_t v;
        v[0] = (_Float16)tile[tx][2 * kp];
        v[1] = (_Float16)tile[tx][2 * kp + 1];
        Wp2[(size_t)((x0 >> 1) + kp) * DLAT + y0 + tx] = v;
    }
}

// ---------------- Kernel B: scan with W_h fully CU-resident (VGPR + LDS) ---------
// One batch row per WG; 512 threads = 4 k-groups (kq) x 128 threads (g, owns rows
// 4g..4g+3). Thread's 64 k-pairs: 48 held in VGPRs (192 regs), 16 in LDS
// ([i][tid]-major half8 -> conflict-free ds_read_b128). No per-step global W
// traffic at all; per-step cost = VALU dot2 (1024 cyc/CU) + 128KB LDS (~1500 cyc),
// overlapped. P-row load prefetched at step top, consumed after the barrier.
__global__ __launch_bounds__(512, 2)
void rnn_scan_resident(const half2_t* __restrict__ Wp2,  // [256 kp][512 r]
                       const float* __restrict__ h0,
                       float* __restrict__ out)
{
    __shared__ half8_t ldsW[16 * 512];     // 128 KB: ldsW[i][tid], i = kp-local-48
    __shared__ float   p[4][DLAT];         // 8 KB partials
    __shared__ half2_t hh[DLAT / 2];       // 1 KB h (fp16 pairs)

    const int b   = blockIdx.x;
    const int tid = threadIdx.x;
    const int kq  = tid >> 7;              // 0..3: k-pairs [kq*64, kq*64+64)
    const int g   = tid & 127;             // 0..127: output rows 4g..4g+3

    // ---- one-time: load weights into VGPRs (48 kp) and LDS (16 kp) ----
    const half8_t* wg = (const half8_t*)Wp2;   // index = kp*128 + r/4
    half8_t wreg[48];
    #pragma unroll
    for (int i = 0; i < 48; ++i)
        wreg[i] = wg[(size_t)(kq * 64 + i) * 128 + g];
    #pragma unroll
    for (int i = 0; i < 16; ++i)
        ldsW[i * 512 + tid] = wg[(size_t)(kq * 64 + 48 + i) * 128 + g];

    {
        float v = h0[(size_t)b * DLAT + tid];
        ((_Float16*)hh)[tid] = (_Float16)v;    // h0 used pre-relu (negatives count)
    }
    __syncthreads();

    for (int t = 0; t < TSTEPS; ++t) {
        float* orow = out + ((size_t)t * BATCH + b) * DLAT;
        float pv = orow[tid];               // prefetch P; consumed after barrier
        float4 acc = make_float4(0.f, 0.f, 0.f, 0.f);

        // ---- VGPR-resident part: kp-local 0..47 (3 chunks of 16) ----
        #pragma unroll
        for (int c = 0; c < 3; ++c) {
            half8_t h8[4];
            #pragma unroll
            for (int q = 0; q < 4; ++q)
                h8[q] = *(const half8_t*)&hh[kq * 64 + c * 16 + q * 4];  // broadcast
            #pragma unroll
            for (int i = 0; i < 16; ++i) {
                half2_t hv = { h8[i >> 2][(i & 3) * 2], h8[i >> 2][(i & 3) * 2 + 1] };
                DOT4(wreg[c * 16 + i], hv);
            }
        }
        // ---- LDS-resident part: kp-local 48..63 ----
        {
            half8_t h8[4];
            #pragma unroll
            for (int q = 0; q < 4; ++q)
                h8[q] = *(const half8_t*)&hh[kq * 64 + 48 + q * 4];
            #pragma unroll
            for (int i = 0; i < 16; ++i) {
                half8_t w = ldsW[i * 512 + tid];   // b128, conflict-free
                half2_t hv = { h8[i >> 2][(i & 3) * 2], h8[i >> 2][(i & 3) * 2 + 1] };
                DOT4(w, hv);
            }
        }

        *(float4*)&p[kq][g * 4] = acc;
        __syncthreads();                    // partials ready; hh reads done

        float v = pv + p[0][tid] + p[1][tid] + p[2][tid] + p[3][tid];
        v = fmaxf(v, 0.f);
        orow[tid] = v;
        ((_Float16*)hh)[tid] = (_Float16)v;
        __syncthreads();                    // hh ready for next step
    }
}

// ---------------- Fallback (no workspace): row-major W_h, one row per thread ----
__global__ __launch_bounds__(512)
void rnn_scan_row(const float* __restrict__ Wh,
                  const float* __restrict__ h0,
                  float* __restrict__ out)
{
    __shared__ float h[DLAT];
    const int b = blockIdx.x;
    const int r = threadIdx.x;
    h[r] = h0[(size_t)b * DLAT + r];
    __syncthreads();
    const float* wrow = Wh + (size_t)r * DLAT;
    for (int t = 0; t < TSTEPS; ++t) {
        float* orow = out + ((size_t)t * BATCH + b) * DLAT;
        float acc = orow[r];
        #pragma unroll 8
        for (int k = 0; k < DLAT; k += 4) {
            float4 w  = *(const float4*)(wrow + k);
            float4 hv = *(const float4*)&h[k];
            acc += w.x*hv.x + w.y*hv.y + w.z*hv.z + w.w*hv.w;
        }
        float v = fmaxf(acc, 0.f);
        __syncthreads();
        h[r] = v;
        orow[r] = v;
        __syncthreads();
    }
}

extern "C" void kernel_launch(void* const* d_in, const int* in_sizes, int n_in,
                              void* d_out, int out_size, void* d_ws, size_t ws_size,
                              hipStream_t stream)
{
    const float* x    = (const float*)d_in[0];
    const float* h0   = (const float*)d_in[1];
    const float* Win  = (const float*)d_in[2];
    const float* Wh   = (const float*)d_in[3];
    const float* bh   = (const float*)d_in[4];
    float* out = (float*)d_out;

    dim3 gA(DLAT / BN, (TSTEPS * BATCH) / BM);   // (8, 512)
    precompute_gemm<<<gA, 256, 0, stream>>>(x, Win, bh, out);

    const size_t wp_bytes = (size_t)(DLAT / 2) * DLAT * sizeof(half2_t);  // 512 KB
    if (ws_size >= wp_bytes) {
        half2_t* Wp2 = (half2_t*)d_ws;
        pack_wh_fp16<<<dim3(16, 16), dim3(32, 8), 0, stream>>>(Wh, Wp2);
        rnn_scan_resident<<<BATCH, 512, 0, stream>>>(Wp2, h0, out);
    } else {
        rnn_scan_row<<<BATCH, 512, 0, stream>>>(Wh, h0, out);
    }
}

// Round 5
// 850.304 us; speedup vs baseline: 5.8685x; 1.0257x over previous
//
#include <hip/hip_runtime.h>

#define TSTEPS 512
#define BATCH  64
#define DIN    256
#define DLAT   512

typedef _Float16 half2_t __attribute__((ext_vector_type(2)));
typedef _Float16 half8_t __attribute__((ext_vector_type(8)));

#if __has_builtin(__builtin_amdgcn_fdot2)
#define FDOT2(a, b, c) __builtin_amdgcn_fdot2((a), (b), (c), false)
#else
#define FDOT2(a, b, c) fmaf((float)(a)[0], (float)(b)[0], fmaf((float)(a)[1], (float)(b)[1], (c)))
#endif

// ---------------- Kernel A: P[m,n] = x[m,:] . W_in[n,:] + b_h[n] ----------------
#define BM 64
#define BN 64
#define BK 32

__global__ __launch_bounds__(256)
void precompute_gemm(const float* __restrict__ x,
                     const float* __restrict__ Win,
                     const float* __restrict__ bh,
                     float* __restrict__ P)
{
    __shared__ float As[BM][BK + 1];
    __shared__ float Ws[BN][BK + 1];
    const int m0  = blockIdx.y * BM;
    const int n0  = blockIdx.x * BN;
    const int tid = threadIdx.x;
    const int tx  = tid & 15;
    const int ty  = tid >> 4;
    const int lr  = tid >> 2;
    const int lc  = (tid & 3) * 8;

    float acc[4][4] = {};

    for (int kk = 0; kk < DIN; kk += BK) {
        const float* ax = x   + (size_t)(m0 + lr) * DIN + kk + lc;
        const float* aw = Win + (size_t)(n0 + lr) * DIN + kk + lc;
        float4 a0 = *(const float4*)(ax);
        float4 a1 = *(const float4*)(ax + 4);
        float4 w0 = *(const float4*)(aw);
        float4 w1 = *(const float4*)(aw + 4);
        As[lr][lc+0]=a0.x; As[lr][lc+1]=a0.y; As[lr][lc+2]=a0.z; As[lr][lc+3]=a0.w;
        As[lr][lc+4]=a1.x; As[lr][lc+5]=a1.y; As[lr][lc+6]=a1.z; As[lr][lc+7]=a1.w;
        Ws[lr][lc+0]=w0.x; Ws[lr][lc+1]=w0.y; Ws[lr][lc+2]=w0.z; Ws[lr][lc+3]=w0.w;
        Ws[lr][lc+4]=w1.x; Ws[lr][lc+5]=w1.y; Ws[lr][lc+6]=w1.z; Ws[lr][lc+7]=w1.w;
        __syncthreads();
        #pragma unroll
        for (int k = 0; k < BK; ++k) {
            float a[4], w[4];
            #pragma unroll
            for (int i = 0; i < 4; ++i) a[i] = As[ty*4+i][k];
            #pragma unroll
            for (int j = 0; j < 4; ++j) w[j] = Ws[tx*4+j][k];
            #pragma unroll
            for (int i = 0; i < 4; ++i)
                #pragma unroll
                for (int j = 0; j < 4; ++j)
                    acc[i][j] += a[i] * w[j];
        }
        __syncthreads();
    }

    float4 bv = *(const float4*)(bh + n0 + tx*4);
    #pragma unroll
    for (int i = 0; i < 4; ++i) {
        float4 v;
        v.x = acc[i][0] + bv.x; v.y = acc[i][1] + bv.y;
        v.z = acc[i][2] + bv.z; v.w = acc[i][3] + bv.w;
        *(float4*)(P + (size_t)(m0 + ty*4 + i) * DLAT + n0 + tx*4) = v;
    }
}

// -------- Pack W_h (512x512 fp32 row-major [r][k]) into fp16 k-pair layout -------
// Wp2[kp][r] = half2( W_h[r][2kp], W_h[r][2kp+1] ), kp in [0,256), r in [0,512).
__global__ __launch_bounds__(256)
void pack_wh_fp16(const float* __restrict__ Wh, half2_t* __restrict__ Wp2)
{
    __shared__ float tile[32][33];
    const int x0 = blockIdx.x * 32;    // k tile
    const int y0 = blockIdx.y * 32;    // r tile
    const int tx = threadIdx.x, ty = threadIdx.y;   // (32, 8)
    #pragma unroll
    for (int j = 0; j < 32; j += 8)
        tile[ty + j][tx] = Wh[(size_t)(y0 + ty + j) * DLAT + x0 + tx]; // tile[r][k]
    __syncthreads();
    #pragma unroll
    for (int j = 0; j < 16; j += 8) {
        const int kp = ty + j;                       // 0..15
        half2_t v;
        v[0] = (_Float16)tile[tx][2 * kp];
        v[1] = (_Float16)tile[tx][2 * kp + 1];
        Wp2[(size_t)((x0 >> 1) + kp) * DLAT + y0 + tx] = v;
    }
}

// ---------------- Kernel B: resident scan, 8 waves = 8 k-groups ------------------
// One batch row per WG; 512 threads = 8 waves; wave kq owns k-pairs
// [kq*32, kq*32+32); lane g owns output rows 8g..8g+7. Per (kp, thread): 8 rows
// = 2 half8 (32B). W split: 26 kp in VGPRs (208 regs), 6 kp in LDS (96 KB,
// [slot][tid]-major b128 conflict-free). hh reads are wave-uniform (whole wave
// = one kq) -> broadcast. amdgpu_waves_per_eu(2,2) pins occupancy so the
// allocator can use the full 256-VGPR budget instead of AGPR-splitting at 128.
__global__ __launch_bounds__(512, 2) __attribute__((amdgpu_waves_per_eu(2, 2)))
void rnn_scan_resident8(const half2_t* __restrict__ Wp2,  // [256 kp][512 r]
                        const float* __restrict__ h0,
                        float* __restrict__ out)
{
    __shared__ half8_t ldsW[12 * 512];     // 96 KB: ldsW[slot][tid]
    __shared__ float   p[8][DLAT];         // 16 KB partials
    __shared__ half2_t hh[DLAT / 2];       // 1 KB h (fp16 pairs)

    const int b   = blockIdx.x;
    const int tid = threadIdx.x;
    const int kq  = tid >> 6;              // 0..7 == wave id
    const int g   = tid & 63;              // lane: rows 8g..8g+7

    // ---- one-time: weights into VGPRs (kp-local 0..25) and LDS (26..31) ----
    const half8_t* wg = (const half8_t*)Wp2;   // index = kp*128 + r/4
    half8_t wreg[52];
    #pragma unroll
    for (int i = 0; i < 26; ++i) {
        wreg[2*i]   = wg[(size_t)(kq * 32 + i) * 128 + g * 2];
        wreg[2*i+1] = wg[(size_t)(kq * 32 + i) * 128 + g * 2 + 1];
    }
    #pragma unroll
    for (int i = 0; i < 6; ++i) {
        ldsW[(2*i)   * 512 + tid] = wg[(size_t)(kq * 32 + 26 + i) * 128 + g * 2];
        ldsW[(2*i+1) * 512 + tid] = wg[(size_t)(kq * 32 + 26 + i) * 128 + g * 2 + 1];
    }

    {
        float v = h0[(size_t)b * DLAT + tid];
        ((_Float16*)hh)[tid] = (_Float16)v;    // h0 used pre-relu
    }
    __syncthreads();

    for (int t = 0; t < TSTEPS; ++t) {
        float* orow = out + ((size_t)t * BATCH + b) * DLAT;
        float pv = orow[tid];               // prefetch P; consumed after barrier
        float acc[8] = {0.f,0.f,0.f,0.f,0.f,0.f,0.f,0.f};

        // 4 chunks of 8 k-pairs; hh reads are wave-uniform broadcast b128
        #pragma unroll
        for (int c = 0; c < 4; ++c) {
            half8_t h8a = *(const half8_t*)&hh[kq * 32 + c * 8];      // kp c*8..+3
            half8_t h8b = *(const half8_t*)&hh[kq * 32 + c * 8 + 4];  // kp c*8+4..+7
            #pragma unroll
            for (int i = 0; i < 8; ++i) {
                const int kpl = c * 8 + i;             // compile-time constant
                half2_t hv;
                if (i < 4) { hv[0] = h8a[i * 2];       hv[1] = h8a[i * 2 + 1]; }
                else       { hv[0] = h8b[(i-4) * 2];   hv[1] = h8b[(i-4) * 2 + 1]; }
                half8_t w0, w1;
                if (kpl < 26) {
                    w0 = wreg[2 * kpl];
                    w1 = wreg[2 * kpl + 1];
                } else {
                    w0 = ldsW[(2 * (kpl - 26))     * 512 + tid];
                    w1 = ldsW[(2 * (kpl - 26) + 1) * 512 + tid];
                }
                half2_t a0 = {w0[0], w0[1]}, a1 = {w0[2], w0[3]};
                half2_t a2 = {w0[4], w0[5]}, a3 = {w0[6], w0[7]};
                half2_t a4 = {w1[0], w1[1]}, a5 = {w1[2], w1[3]};
                half2_t a6 = {w1[4], w1[5]}, a7 = {w1[6], w1[7]};
                acc[0] = FDOT2(a0, hv, acc[0]);
                acc[1] = FDOT2(a1, hv, acc[1]);
                acc[2] = FDOT2(a2, hv, acc[2]);
                acc[3] = FDOT2(a3, hv, acc[3]);
                acc[4] = FDOT2(a4, hv, acc[4]);
                acc[5] = FDOT2(a5, hv, acc[5]);
                acc[6] = FDOT2(a6, hv, acc[6]);
                acc[7] = FDOT2(a7, hv, acc[7]);
            }
        }

        *(float4*)&p[kq][g * 8]     = make_float4(acc[0], acc[1], acc[2], acc[3]);
        *(float4*)&p[kq][g * 8 + 4] = make_float4(acc[4], acc[5], acc[6], acc[7]);
        __syncthreads();                    // partials ready; hh reads done

        float v = pv;
        #pragma unroll
        for (int q = 0; q < 8; ++q) v += p[q][tid];
        v = fmaxf(v, 0.f);
        orow[tid] = v;
        ((_Float16*)hh)[tid] = (_Float16)v;
        __syncthreads();                    // hh ready for next step
    }
}

// ---------------- Fallback (no workspace): row-major W_h, one row per thread ----
__global__ __launch_bounds__(512)
void rnn_scan_row(const float* __restrict__ Wh,
                  const float* __restrict__ h0,
                  float* __restrict__ out)
{
    __shared__ float h[DLAT];
    const int b = blockIdx.x;
    const int r = threadIdx.x;
    h[r] = h0[(size_t)b * DLAT + r];
    __syncthreads();
    const float* wrow = Wh + (size_t)r * DLAT;
    for (int t = 0; t < TSTEPS; ++t) {
        float* orow = out + ((size_t)t * BATCH + b) * DLAT;
        float acc = orow[r];
        #pragma unroll 8
        for (int k = 0; k < DLAT; k += 4) {
            float4 w  = *(const float4*)(wrow + k);
            float4 hv = *(const float4*)&h[k];
            acc += w.x*hv.x + w.y*hv.y + w.z*hv.z + w.w*hv.w;
        }
        float v = fmaxf(acc, 0.f);
        __syncthreads();
        h[r] = v;
        orow[r] = v;
        __syncthreads();
    }
}

extern "C" void kernel_launch(void* const* d_in, const int* in_sizes, int n_in,
                              void* d_out, int out_size, void* d_ws, size_t ws_size,
                              hipStream_t stream)
{
    const float* x    = (const float*)d_in[0];
    const float* h0   = (const float*)d_in[1];
    const float* Win  = (const float*)d_in[2];
    const float* Wh   = (const float*)d_in[3];
    const float* bh   = (const float*)d_in[4];
    float* out = (float*)d_out;

    dim3 gA(DLAT / BN, (TSTEPS * BATCH) / BM);   // (8, 512)
    precompute_gemm<<<gA, 256, 0, stream>>>(x, Win, bh, out);

    const size_t wp_bytes = (size_t)(DLAT / 2) * DLAT * sizeof(half2_t);  // 512 KB
    if (ws_size >= wp_bytes) {
        half2_t* Wp2 = (half2_t*)d_ws;
        pack_wh_fp16<<<dim3(16, 16), dim3(32, 8), 0, stream>>>(Wh, Wp2);
        rnn_scan_resident8<<<BATCH, 512, 0, stream>>>(Wp2, h0, out);
    } else {
        rnn_scan_row<<<BATCH, 512, 0, stream>>>(Wh, h0, out);
    }
}

// Round 6
// 844.788 us; speedup vs baseline: 5.9068x; 1.0065x over previous
//
#include <hip/hip_runtime.h>

#define TSTEPS 512
#define BATCH  64
#define DIN    256
#define DLAT   512

typedef _Float16 half2_t __attribute__((ext_vector_type(2)));
typedef _Float16 half8_t __attribute__((ext_vector_type(8)));

#if __has_builtin(__builtin_amdgcn_fdot2)
#define FDOT2(a, b, c) __builtin_amdgcn_fdot2((a), (b), (c), false)
#else
#define FDOT2(a, b, c) fmaf((float)(a)[0], (float)(b)[0], fmaf((float)(a)[1], (float)(b)[1], (c)))
#endif

// extract half2 word j (compile-time) from a half8 register quad — register
// aliasing only, no VALU
__device__ __forceinline__ half2_t h2w(half8_t v, int j) {
    half2_t r; r[0] = v[2 * j]; r[1] = v[2 * j + 1]; return r;
}

// ---------------- Kernel A: P[m,n] = x[m,:] . W_in[n,:] + b_h[n] ----------------
#define BM 64
#define BN 64
#define BK 32

__global__ __launch_bounds__(256)
void precompute_gemm(const float* __restrict__ x,
                     const float* __restrict__ Win,
                     const float* __restrict__ bh,
                     float* __restrict__ P)
{
    __shared__ float As[BM][BK + 1];
    __shared__ float Ws[BN][BK + 1];
    const int m0  = blockIdx.y * BM;
    const int n0  = blockIdx.x * BN;
    const int tid = threadIdx.x;
    const int tx  = tid & 15;
    const int ty  = tid >> 4;
    const int lr  = tid >> 2;
    const int lc  = (tid & 3) * 8;

    float acc[4][4] = {};

    for (int kk = 0; kk < DIN; kk += BK) {
        const float* ax = x   + (size_t)(m0 + lr) * DIN + kk + lc;
        const float* aw = Win + (size_t)(n0 + lr) * DIN + kk + lc;
        float4 a0 = *(const float4*)(ax);
        float4 a1 = *(const float4*)(ax + 4);
        float4 w0 = *(const float4*)(aw);
        float4 w1 = *(const float4*)(aw + 4);
        As[lr][lc+0]=a0.x; As[lr][lc+1]=a0.y; As[lr][lc+2]=a0.z; As[lr][lc+3]=a0.w;
        As[lr][lc+4]=a1.x; As[lr][lc+5]=a1.y; As[lr][lc+6]=a1.z; As[lr][lc+7]=a1.w;
        Ws[lr][lc+0]=w0.x; Ws[lr][lc+1]=w0.y; Ws[lr][lc+2]=w0.z; Ws[lr][lc+3]=w0.w;
        Ws[lr][lc+4]=w1.x; Ws[lr][lc+5]=w1.y; Ws[lr][lc+6]=w1.z; Ws[lr][lc+7]=w1.w;
        __syncthreads();
        #pragma unroll
        for (int k = 0; k < BK; ++k) {
            float a[4], w[4];
            #pragma unroll
            for (int i = 0; i < 4; ++i) a[i] = As[ty*4+i][k];
            #pragma unroll
            for (int j = 0; j < 4; ++j) w[j] = Ws[tx*4+j][k];
            #pragma unroll
            for (int i = 0; i < 4; ++i)
                #pragma unroll
                for (int j = 0; j < 4; ++j)
                    acc[i][j] += a[i] * w[j];
        }
        __syncthreads();
    }

    float4 bv = *(const float4*)(bh + n0 + tx*4);
    #pragma unroll
    for (int i = 0; i < 4; ++i) {
        float4 v;
        v.x = acc[i][0] + bv.x; v.y = acc[i][1] + bv.y;
        v.z = acc[i][2] + bv.z; v.w = acc[i][3] + bv.w;
        *(float4*)(P + (size_t)(m0 + ty*4 + i) * DLAT + n0 + tx*4) = v;
    }
}

// -------- Pack W_h (512x512 fp32 row-major [r][k]) into fp16 k-pair layout -------
// Wp2[kp][r] = half2( W_h[r][2kp], W_h[r][2kp+1] ), kp in [0,256), r in [0,512).
__global__ __launch_bounds__(256)
void pack_wh_fp16(const float* __restrict__ Wh, half2_t* __restrict__ Wp2)
{
    __shared__ float tile[32][33];
    const int x0 = blockIdx.x * 32;    // k tile
    const int y0 = blockIdx.y * 32;    // r tile
    const int tx = threadIdx.x, ty = threadIdx.y;   // (32, 8)
    #pragma unroll
    for (int j = 0; j < 32; j += 8)
        tile[ty + j][tx] = Wh[(size_t)(y0 + ty + j) * DLAT + x0 + tx]; // tile[r][k]
    __syncthreads();
    #pragma unroll
    for (int j = 0; j < 16; j += 8) {
        const int kp = ty + j;                       // 0..15
        half2_t v;
        v[0] = (_Float16)tile[tx][2 * kp];
        v[1] = (_Float16)tile[tx][2 * kp + 1];
        Wp2[(size_t)((x0 >> 1) + kp) * DLAT + y0 + tx] = v;
    }
}

// ---------------- Kernel B: scan, W maximally register-resident -----------------
// One batch row per WG; 512 threads = 8 waves. Wave w owns k-range
// [64w, 64w+64) = 32 k-pairs: 27 kp in registers (216 regs; compiler splits
// arch VGPR + AGPR within the 256 budget at 2 waves/EU), 5 kp in LDS (80 KB).
// Lane g owns output rows {4g..4g+3} and {256+4g..256+4g+3} -> partial writes
// are two float4s at 16B lane stride (conflict-free; fixes R5's 4.19M
// SQ_LDS_BANK_CONFLICT from 32B-stride writes). h (fp16 pairs, 1 KB) read as
// wave-uniform half8 broadcasts, one 4-reg chunk live at a time.
__global__ __launch_bounds__(512, 2) __attribute__((amdgpu_waves_per_eu(2, 2)))
void rnn_scan_reg(const half2_t* __restrict__ Wp2,  // [256 kp][512 r]
                  const float* __restrict__ h0,
                  float* __restrict__ out)
{
    __shared__ half8_t ldsW[10 * 512];     // 80 KB: kp-local 27..31, [slot][tid]
    __shared__ float   p[8][DLAT];         // 16 KB partials
    __shared__ half2_t hh[DLAT / 2];       // 1 KB h (fp16 pairs)

    const int b   = blockIdx.x;
    const int tid = threadIdx.x;
    const int w   = tid >> 6;              // wave id == k-group
    const int g   = tid & 63;              // lane

    // ---- one-time: weights into registers (27 kp) and LDS (5 kp) ----
    const half8_t* wg = (const half8_t*)Wp2;   // index = kp*128 + r/4
    half8_t wra[27], wrb[27];              // rows 4g..4g+3 / 256+4g..256+4g+3
    #pragma unroll
    for (int i = 0; i < 27; ++i) {
        wra[i] = wg[(size_t)(w * 32 + i) * 128 + g];
        wrb[i] = wg[(size_t)(w * 32 + i) * 128 + 64 + g];
    }
    #pragma unroll
    for (int i = 0; i < 5; ++i) {
        ldsW[(2*i+0) * 512 + tid] = wg[(size_t)(w * 32 + 27 + i) * 128 + g];
        ldsW[(2*i+1) * 512 + tid] = wg[(size_t)(w * 32 + 27 + i) * 128 + 64 + g];
    }

    ((_Float16*)hh)[tid] = (_Float16)h0[(size_t)b * DLAT + tid];  // pre-relu h0
    __syncthreads();

    for (int t = 0; t < TSTEPS; ++t) {
        float* orow = out + ((size_t)t * BATCH + b) * DLAT;
        float pv = orow[tid];               // prefetch P; consumed after barrier
        float4 accA = make_float4(0.f, 0.f, 0.f, 0.f);
        float4 accB = make_float4(0.f, 0.f, 0.f, 0.f);

        #pragma unroll
        for (int c = 0; c < 8; ++c) {
            // wave-uniform broadcast: 4 k-pairs (16B) of h for this chunk
            half8_t hc = *(const half8_t*)&hh[w * 32 + c * 4];
            #pragma unroll
            for (int j = 0; j < 4; ++j) {
                const int i = c * 4 + j;           // kp-local 0..31 (compile-time)
                half2_t hv = h2w(hc, j);
                half8_t wA, wB;
                if (i < 27) {
                    wA = wra[i];
                    wB = wrb[i];
                } else {
                    wA = ldsW[(2*(i-27)+0) * 512 + tid];
                    wB = ldsW[(2*(i-27)+1) * 512 + tid];
                }
                accA.x = FDOT2(h2w(wA, 0), hv, accA.x);
                accA.y = FDOT2(h2w(wA, 1), hv, accA.y);
                accA.z = FDOT2(h2w(wA, 2), hv, accA.z);
                accA.w = FDOT2(h2w(wA, 3), hv, accA.w);
                accB.x = FDOT2(h2w(wB, 0), hv, accB.x);
                accB.y = FDOT2(h2w(wB, 1), hv, accB.y);
                accB.z = FDOT2(h2w(wB, 2), hv, accB.z);
                accB.w = FDOT2(h2w(wB, 3), hv, accB.w);
            }
        }

        *(float4*)&p[w][4 * g]       = accA;   // 16B lane stride: conflict-free
        *(float4*)&p[w][256 + 4 * g] = accB;
        __syncthreads();                    // partials ready; hh reads done

        float v = pv;
        #pragma unroll
        for (int q = 0; q < 8; ++q) v += p[q][tid];
        v = fmaxf(v, 0.f);
        orow[tid] = v;
        ((_Float16*)hh)[tid] = (_Float16)v;
        __syncthreads();                    // hh ready for next step
    }
}

// ---------------- Fallback (no workspace): row-major W_h, one row per thread ----
__global__ __launch_bounds__(512)
void rnn_scan_row(const float* __restrict__ Wh,
                  const float* __restrict__ h0,
                  float* __restrict__ out)
{
    __shared__ float h[DLAT];
    const int b = blockIdx.x;
    const int r = threadIdx.x;
    h[r] = h0[(size_t)b * DLAT + r];
    __syncthreads();
    const float* wrow = Wh + (size_t)r * DLAT;
    for (int t = 0; t < TSTEPS; ++t) {
        float* orow = out + ((size_t)t * BATCH + b) * DLAT;
        float acc = orow[r];
        #pragma unroll 8
        for (int k = 0; k < DLAT; k += 4) {
            float4 w  = *(const float4*)(wrow + k);
            float4 hv = *(const float4*)&h[k];
            acc += w.x*hv.x + w.y*hv.y + w.z*hv.z + w.w*hv.w;
        }
        float v = fmaxf(acc, 0.f);
        __syncthreads();
        h[r] = v;
        orow[r] = v;
        __syncthreads();
    }
}

extern "C" void kernel_launch(void* const* d_in, const int* in_sizes, int n_in,
                              void* d_out, int out_size, void* d_ws, size_t ws_size,
                              hipStream_t stream)
{
    const float* x    = (const float*)d_in[0];
    const float* h0   = (const float*)d_in[1];
    const float* Win  = (const float*)d_in[2];
    const float* Wh   = (const float*)d_in[3];
    const float* bh   = (const float*)d_in[4];
    float* out = (float*)d_out;

    dim3 gA(DLAT / BN, (TSTEPS * BATCH) / BM);   // (8, 512)
    precompute_gemm<<<gA, 256, 0, stream>>>(x, Win, bh, out);

    const size_t wp_bytes = (size_t)(DLAT / 2) * DLAT * sizeof(half2_t);  // 512 KB
    if (ws_size >= wp_bytes) {
        half2_t* Wp2 = (half2_t*)d_ws;
        pack_wh_fp16<<<dim3(16, 16), dim3(32, 8), 0, stream>>>(Wh, Wp2);
        rnn_scan_reg<<<BATCH, 512, 0, stream>>>(Wp2, h0, out);
    } else {
        rnn_scan_row<<<BATCH, 512, 0, stream>>>(Wh, h0, out);
    }
}